// Round 2
// baseline (209.052 us; speedup 1.0000x reference)
//
#include <hip/hip_runtime.h>

// x: (32, 1024, 1024) f32; segment_ids: (32, 1024) int32 (harness casts int64->int32)
// lo=257 -> 512 tokens/batch, 16384 tokens total
// out: (2048, 2048) f32 = per-segment mean of [x[b,257+t,0:1024] ++ x[b,0,0:1024]]
#define NBATCH 32
#define TOK 512
#define NTOK (NBATCH * TOK)      // 16384
#define NSEG 2048
#define LO 257
#define XROW 1024
#define XBATCH (1024 * 1024)
#define SEGROW 1024
#define MAXTOK 64                // Poisson(8): P(count >= 64) ~ 1e-35; clamp for safety

// One block per segment. Phase 1: scan all seg ids (L2-hot, 64KB used slice),
// collect this segment's token indices into LDS. Phase 2: float4 gather+mean.
__global__ __launch_bounds__(256) void k_fused(const float* __restrict__ x,
                                               const int* __restrict__ seg_ids,
                                               float* __restrict__ out) {
    __shared__ int toks[MAXTOK];
    __shared__ int s_cnt;
    const int seg = blockIdx.x;
    const int tid = threadIdx.x;
    if (tid == 0) s_cnt = 0;
    __syncthreads();

    // Phase 1: 64 ids per thread, coalesced (contiguous within each batch row).
#pragma unroll 4
    for (int i = tid; i < NTOK; i += 256) {
        int b = i >> 9, t = i & 511;
        int s = seg_ids[b * SEGROW + LO + t];
        if (s == seg) {
            int p = atomicAdd(&s_cnt, 1);
            if (p < MAXTOK) toks[p] = i;
        }
    }
    __syncthreads();
    int n = s_cnt;
    if (n > MAXTOK) n = MAXTOK;

    // Phase 2: thread tid owns float4 [4*tid .. 4*tid+3] of each output half.
    float4 a1 = make_float4(0.f, 0.f, 0.f, 0.f);  // emb half
    float4 a2 = make_float4(0.f, 0.f, 0.f, 0.f);  // cls half
    for (int i = 0; i < n; i++) {
        int id = toks[i];
        int b = id >> 9, t = id & 511;
        const float4* emb = (const float4*)(x + (size_t)b * XBATCH + (size_t)(LO + t) * XROW);
        const float4* cls = (const float4*)(x + (size_t)b * XBATCH);
        float4 e = emb[tid];
        float4 c = cls[tid];
        a1.x += e.x; a1.y += e.y; a1.z += e.z; a1.w += e.w;
        a2.x += c.x; a2.y += c.y; a2.z += c.z; a2.w += c.w;
    }
    float inv = (n > 0) ? (1.0f / (float)n) : 1.0f;   // n==0 -> accumulators are 0
    a1.x *= inv; a1.y *= inv; a1.z *= inv; a1.w *= inv;
    a2.x *= inv; a2.y *= inv; a2.z *= inv; a2.w *= inv;

    float4* o = (float4*)(out + (size_t)seg * 2048);
    o[tid] = a1;          // features 0..1023
    o[256 + tid] = a2;    // features 1024..2047
}

extern "C" void kernel_launch(void* const* d_in, const int* in_sizes, int n_in,
                              void* d_out, int out_size, void* d_ws, size_t ws_size,
                              hipStream_t stream) {
    const float* x = (const float*)d_in[0];
    const int* seg_ids = (const int*)d_in[1];
    float* out = (float*)d_out;
    k_fused<<<NSEG, 256, 0, stream>>>(x, seg_ids, out);
}

// Round 3
// 191.970 us; speedup vs baseline: 1.0890x; 1.0890x over previous
//
#include <hip/hip_runtime.h>

// x: (32, 1024, 1024) f32; segment_ids: (32, 1024) int32
// slice rows r in [257, 768] (512 tokens/batch, 16384 total)
// out: (2048, 2048) f32 = per-segment mean of [x[b,r,0:1024] ++ x[b,0,0:1024]]
#define NBATCH 32
#define NSEG 2048
#define LO 257
#define XROW 1024
#define XBATCH (1024 * 1024)
#define SEGROW 1024
#define MAXTOK 64   // Poisson(8): P(>=64) ~ 1e-35

// One block per segment.
// Phase 1: int4-vectorized scan of seg_ids rows [256,768) (16B-aligned) + r=768 edge.
//          Matches -> token list in LDS + per-batch match counts.
// Phase 2: emb half gathered per token (float4, coalesced); cls half computed as
//          sum_b cnt_b * cls_row_b (cls rows are L2-hot, loaded once per present batch).
__global__ __launch_bounds__(256) void k_fused(const float* __restrict__ x,
                                               const int* __restrict__ seg_ids,
                                               float* __restrict__ out) {
    __shared__ int toks[MAXTOK];
    __shared__ int s_cntb[NBATCH];
    __shared__ int s_cnt;
    const int seg = blockIdx.x;
    const int tid = threadIdx.x;
    if (tid < NBATCH) s_cntb[tid] = 0;
    if (tid == 0) s_cnt = 0;
    __syncthreads();

    // Phase 1a: vector scan. Row b, int4 j covers ids r = 256+4j .. 259+4j, j in [0,128).
    const int4* seg4 = (const int4*)seg_ids;
#pragma unroll 4
    for (int v = tid; v < NBATCH * 128; v += 256) {
        int b = v >> 7, j = v & 127;
        int4 q = seg4[b * (SEGROW / 4) + 64 + j];
        int rbase = 256 + 4 * j;
        int ids[4] = {q.x, q.y, q.z, q.w};
#pragma unroll
        for (int k = 0; k < 4; k++) {
            int r = rbase + k;
            if (r >= LO && ids[k] == seg) {   // r <= 767 always here
                int p = atomicAdd(&s_cnt, 1);
                if (p < MAXTOK) toks[p] = b * 512 + (r - LO);
                atomicAdd(&s_cntb[b], 1);
            }
        }
    }
    // Phase 1b: edge r = 768 (one per batch).
    if (tid < NBATCH) {
        int s = seg_ids[tid * SEGROW + 768];
        if (s == seg) {
            int p = atomicAdd(&s_cnt, 1);
            if (p < MAXTOK) toks[p] = tid * 512 + 511;
            atomicAdd(&s_cntb[tid], 1);
        }
    }
    __syncthreads();
    int n = s_cnt;
    int n8 = n > MAXTOK ? MAXTOK : n;

    // Phase 2: thread tid owns float4 [4*tid..4*tid+3] of each output half.
    float4 a1 = make_float4(0.f, 0.f, 0.f, 0.f);  // emb half
    float4 a2 = make_float4(0.f, 0.f, 0.f, 0.f);  // cls half
    for (int i = 0; i < n8; i++) {
        int id = toks[i];
        int b = id >> 9, t = id & 511;
        float4 e = ((const float4*)(x + (size_t)b * XBATCH + (size_t)(LO + t) * XROW))[tid];
        a1.x += e.x; a1.y += e.y; a1.z += e.z; a1.w += e.w;
    }
#pragma unroll
    for (int b = 0; b < NBATCH; b++) {
        int c = s_cntb[b];
        if (c > 0) {
            float fc = (float)c;
            float4 cl = ((const float4*)(x + (size_t)b * XBATCH))[tid];
            a2.x += fc * cl.x; a2.y += fc * cl.y; a2.z += fc * cl.z; a2.w += fc * cl.w;
        }
    }
    float inv = (n > 0) ? (1.0f / (float)n) : 1.0f;
    a1.x *= inv; a1.y *= inv; a1.z *= inv; a1.w *= inv;
    a2.x *= inv; a2.y *= inv; a2.z *= inv; a2.w *= inv;

    float4* o = (float4*)(out + (size_t)seg * 2048);
    o[tid] = a1;
    o[256 + tid] = a2;
}

extern "C" void kernel_launch(void* const* d_in, const int* in_sizes, int n_in,
                              void* d_out, int out_size, void* d_ws, size_t ws_size,
                              hipStream_t stream) {
    const float* x = (const float*)d_in[0];
    const int* seg_ids = (const int*)d_in[1];
    float* out = (float*)d_out;
    k_fused<<<NSEG, 256, 0, stream>>>(x, seg_ids, out);
}